// Round 1
// baseline (565.371 us; speedup 1.0000x reference)
//
#include <hip/hip_runtime.h>
#include <hip/hip_bf16.h>
#include <stdint.h>

// Problem constants
#define N_ROWS 8192
#define IN_F   4096
#define OUT_F  4096
#define R_LORA 16
#define KP     4160   // padded K: 4096 data + col 4096 = bias-1.0 trick + zeros to /64

typedef __bf16 bf16_t;
typedef __attribute__((ext_vector_type(8))) __bf16 bf16x8;
typedef __attribute__((ext_vector_type(4))) __bf16 bf16x4;
typedef __attribute__((ext_vector_type(4))) float  f32x4;
typedef __attribute__((ext_vector_type(16))) float f32x16;

// ---------------------------------------------------------------------------
// async global->LDS, 16B per lane. LDS dest must be wave_base + lane*16.
// Per-lane SOURCE address is free-form (gather) — only the dest is constrained.
__device__ __forceinline__ void load16_lds(const bf16_t* g, bf16_t* l) {
    auto gp = (const __attribute__((address_space(1))) void*)g;
    auto lp = (__attribute__((address_space(3))) void*)(uint32_t)(uintptr_t)l;
    __builtin_amdgcn_global_load_lds(gp, lp, 16, 0, 0);
}

// ---------------------------------------------------------------------------
// Fused prep: blocks [0,2048) build Aw (4 rows each); blocks [2048,3072)
// build Bw (4 o-rows each). Unchanged this round (next optimization target).
#define PREPA_BLOCKS 2048

__global__ __launch_bounds__(256) void prep_fused(const float* __restrict__ x,
                                                  const float* __restrict__ W,
                                                  const float* __restrict__ bias,
                                                  const float* __restrict__ lA,
                                                  const float* __restrict__ lB,
                                                  bf16_t* __restrict__ Aw,
                                                  bf16_t* __restrict__ Bw) {
    int b = blockIdx.x;
    int t = threadIdx.x;
    if (b < PREPA_BLOCKS) {
        int row0 = b * 4;
        for (int rr = 0; rr < 4; ++rr) {
            int row = row0 + rr;
            const float4* xr = (const float4*)(x + (size_t)row * IN_F);
            bf16_t* ar = Aw + (size_t)row * KP;
            for (int s = t; s < 512; s += 256) {
                float4 f0 = xr[2 * s];
                float4 f1 = xr[2 * s + 1];
                bf16x8 v;
                v[0] = (bf16_t)f0.x; v[1] = (bf16_t)f0.y;
                v[2] = (bf16_t)f0.z; v[3] = (bf16_t)f0.w;
                v[4] = (bf16_t)f1.x; v[5] = (bf16_t)f1.y;
                v[6] = (bf16_t)f1.z; v[7] = (bf16_t)f1.w;
                *(bf16x8*)(ar + s * 8) = v;
            }
            if (t < 64) ar[IN_F + t] = (t == 0) ? (bf16_t)1.0f : (bf16_t)0.0f;
        }
    } else {
        int o0 = (b - PREPA_BLOCKS) * 4;
        float bl[4][R_LORA];
        for (int oo = 0; oo < 4; ++oo)
            for (int r = 0; r < R_LORA; ++r)
                bl[oo][r] = 2.0f * lB[(o0 + oo) * R_LORA + r];

        for (int j = 0; j < IN_F / (256 * 4); ++j) {   // 4 iterations
            int i4 = (j * 256 + t) * 4;
            f32x4 acc[4];
            for (int oo = 0; oo < 4; ++oo) {
                float4 w = *(const float4*)(W + (size_t)(o0 + oo) * IN_F + i4);
                acc[oo] = (f32x4){w.x, w.y, w.z, w.w};
            }
            for (int r = 0; r < R_LORA; ++r) {
                float4 a = *(const float4*)(lA + (size_t)r * IN_F + i4);
                for (int oo = 0; oo < 4; ++oo) {
                    acc[oo][0] += bl[oo][r] * a.x;
                    acc[oo][1] += bl[oo][r] * a.y;
                    acc[oo][2] += bl[oo][r] * a.z;
                    acc[oo][3] += bl[oo][r] * a.w;
                }
            }
            for (int oo = 0; oo < 4; ++oo) {
                bf16x4 v;
                v[0] = (bf16_t)acc[oo][0]; v[1] = (bf16_t)acc[oo][1];
                v[2] = (bf16_t)acc[oo][2]; v[3] = (bf16_t)acc[oo][3];
                *(bf16x4*)(Bw + (size_t)(o0 + oo) * KP + i4) = v;
            }
        }
        {   // pad columns: 4 rows x 64 cols = 256 slots, one per thread
            int oo = t >> 6;
            int c  = IN_F + (t & 63);
            float v = (c == IN_F) ? bias[o0 + oo] : 0.0f;
            Bw[(size_t)(o0 + oo) * KP + c] = (bf16_t)v;
        }
    }
}

// ---------------------------------------------------------------------------
// NT bf16 GEMM: C[8192x4096] = Aw[8192xKP] * Bw[4096xKP]^T  (fp32 out)
//
// 256x256 block tile, BK=64, 8 waves in 2x4 (512 thr), 2-deep LDS double
// buffer (128 KiB), 4-phase counted-vmcnt schedule (T3+T4) + setprio (T5)
// + XCD swizzle (T1).
//
// Per K-tile t (buffer b=t&1), 4 phases; phase q computes quadrant
// (qa=q&1 of A-halves, qb=q>>1 of B-halves); each wave owns a 64x32 patch
// per quadrant. Issue order for tile t+1 into buffer b^1 (2 gloads each):
//   phase0: A0   phase1: B0   phase2: A1   phase3: B1
// Steady-state queue trace (2 loads per half-tile):
//   entry:  [A0,B0,A1,B1](t) outstanding<=8 -> vmcnt(4) => A0,B0 landed
//   p0->p1: [A1,B1(t),A0(t+1)]=6 -> vmcnt(4) => A1(t) landed
//   p1->p2: [B1(t),A0,B0(t+1)]=6 -> vmcnt(4) => B1(t) landed
//   p2->p3: nothing new needed -> no wait, no barrier
// Writes always go to the buffer NOT being read (distance-1 prefetch), and
// every issue happens after the tile-entry barrier => no LDS write/read race.
// Never vmcnt(0) in the main loop; tail tile peeled with vmcnt(2)/vmcnt(0).
#define BM 256
#define BN 256
#define BK 64
#define NT (KP / BK)    // 65

#define VMB(n) do { asm volatile("s_waitcnt vmcnt(" #n ")" ::: "memory"); \
                    __builtin_amdgcn_s_barrier(); } while (0)

template<int Q>
__device__ __forceinline__ void phase_mma(const bf16_t* Ab, const bf16_t* Bb,
                                          f32x16 (&acc)[4][2],
                                          int rowA0, int colB0, int lhi, int l7) {
    constexpr int qa = Q & 1, qb = Q >> 1;
    bf16x8 a0[4], a1[4], bb[4];
#pragma unroll
    for (int ks = 0; ks < 4; ++ks) {
        int pos = ((((ks << 1) | lhi)) ^ l7) << 3;   // swizzled 16B chunk
        a0[ks] = *(const bf16x8*)&Ab[(qa * 128 + rowA0) * BK + pos];
        a1[ks] = *(const bf16x8*)&Ab[(qa * 128 + rowA0 + 32) * BK + pos];
        bb[ks] = *(const bf16x8*)&Bb[(qb * 128 + colB0) * BK + pos];
    }
    __builtin_amdgcn_s_setprio(1);
#pragma unroll
    for (int ks = 0; ks < 4; ++ks) {
        acc[Q][0] = __builtin_amdgcn_mfma_f32_32x32x16_bf16(a0[ks], bb[ks], acc[Q][0], 0, 0, 0);
        acc[Q][1] = __builtin_amdgcn_mfma_f32_32x32x16_bf16(a1[ks], bb[ks], acc[Q][1], 0, 0, 0);
    }
    __builtin_amdgcn_s_setprio(0);
}

__global__ __launch_bounds__(512, 2) void gemm_bt(const bf16_t* __restrict__ A,
                                                  const bf16_t* __restrict__ B,
                                                  float* __restrict__ C) {
    __shared__ __align__(16) bf16_t lds[2][2][BM * BK];   // 128 KiB

    int bid = blockIdx.x;
    // XCD-aware bijective swizzle (512 % 8 == 0)
    int swz = (bid & 7) * 64 + (bid >> 3);
    int bm  = swz & 31;              // 8192/256 = 32 row tiles
    int bn  = swz >> 5;              // 4096/256 = 16 col tiles
    int rowBase = bm * BM;
    int colBase = bn * BN;

    const int t    = threadIdx.x;
    const int lane = t & 63;
    const int wave = t >> 6;
    const int l31  = lane & 31;
    const int lhi  = lane >> 5;
    const int l7   = lane & 7;
    const int wr   = wave >> 2;      // 0..1
    const int wcp  = wave & 3;       // 0..3
    const int rowA0 = wr * 64 + l31; // within-half A row (+qa*128, +32 for i=1)
    const int colB0 = wcp * 32 + l31;

    // staging: slot c = s*512 + t, c in [0,2048): r = c>>3 (256 rows),
    // p = c&7. LDS dest is linear (c*16 B => wave base + lane*16, required
    // by global_load_lds); the swizzle lives in the SOURCE chunk p^(r&7).
    uint32_t srcA[4], srcB[4];
#pragma unroll
    for (int s = 0; s < 4; ++s) {
        int c = s * 512 + t;
        int r = c >> 3, p = c & 7;
        uint32_t off = (uint32_t)(r * KP + ((p ^ (r & 7)) << 3));
        srcA[s] = (uint32_t)(rowBase * KP) + off;
        srcB[s] = (uint32_t)(colBase * KP) + off;
    }

    auto stageA = [&](int half, int bsel, int k0) {
#pragma unroll
        for (int s2 = 0; s2 < 2; ++s2) {
            int s = half * 2 + s2;
            load16_lds(A + srcA[s] + k0, &lds[bsel][0][(s * 512 + t) * 8]);
        }
    };
    auto stageB = [&](int half, int bsel, int k0) {
#pragma unroll
        for (int s2 = 0; s2 < 2; ++s2) {
            int s = half * 2 + s2;
            load16_lds(B + srcB[s] + k0, &lds[bsel][1][(s * 512 + t) * 8]);
        }
    };

    f32x16 acc[4][2];
#pragma unroll
    for (int q = 0; q < 4; ++q)
#pragma unroll
        for (int i = 0; i < 2; ++i)
#pragma unroll
            for (int r = 0; r < 16; ++r) acc[q][i][r] = 0.f;

    // prologue: issue all 4 half-tiles of K-tile 0 in order A0,B0,A1,B1
    stageA(0, 0, 0);
    stageB(0, 0, 0);
    stageA(1, 0, 0);
    stageB(1, 0, 0);

    int kt = 0;
    for (; kt < NT - 1; ++kt) {
        const int bsel = kt & 1;
        const int nb   = bsel ^ 1;
        const int k1   = (kt + 1) * BK;
        const bf16_t* Ab = &lds[bsel][0][0];
        const bf16_t* Bb = &lds[bsel][1][0];

        VMB(4);                       // A0,B0(kt) landed
        stageA(0, nb, k1);
        phase_mma<0>(Ab, Bb, acc, rowA0, colB0, lhi, l7);
        VMB(4);                       // A1(kt) landed
        stageB(0, nb, k1);
        phase_mma<1>(Ab, Bb, acc, rowA0, colB0, lhi, l7);
        VMB(4);                       // B1(kt) landed
        stageA(1, nb, k1);
        phase_mma<2>(Ab, Bb, acc, rowA0, colB0, lhi, l7);
        stageB(1, nb, k1);            // no wait needed before phase 3
        phase_mma<3>(Ab, Bb, acc, rowA0, colB0, lhi, l7);
    }
    {   // tail K-tile (kt == NT-1): nothing left to issue
        const int bsel = kt & 1;
        const bf16_t* Ab = &lds[bsel][0][0];
        const bf16_t* Bb = &lds[bsel][1][0];
        VMB(4);                       // A0,B0 landed
        phase_mma<0>(Ab, Bb, acc, rowA0, colB0, lhi, l7);
        VMB(2);                       // A1 landed
        phase_mma<1>(Ab, Bb, acc, rowA0, colB0, lhi, l7);
        VMB(0);                       // B1 landed
        phase_mma<2>(Ab, Bb, acc, rowA0, colB0, lhi, l7);
        phase_mma<3>(Ab, Bb, acc, rowA0, colB0, lhi, l7);
    }

    // epilogue: C/D layout col=l&31, row=(reg&3)+8*(reg>>2)+4*(l>>5)
#pragma unroll
    for (int q = 0; q < 4; ++q) {
        const int qa = q & 1, qb = q >> 1;
#pragma unroll
        for (int i = 0; i < 2; ++i) {
            int rB  = rowBase + qa * 128 + wr * 64 + i * 32 + 4 * lhi;
            int col = colBase + qb * 128 + wcp * 32 + l31;
#pragma unroll
            for (int reg = 0; reg < 16; ++reg) {
                int row = rB + (reg & 3) + 8 * (reg >> 2);
                C[(size_t)row * OUT_F + col] = acc[q][i][reg];
            }
        }
    }
}

// ---------------------------------------------------------------------------
extern "C" void kernel_launch(void* const* d_in, const int* in_sizes, int n_in,
                              void* d_out, int out_size, void* d_ws, size_t ws_size,
                              hipStream_t stream) {
    const float* x  = (const float*)d_in[0];   // (8192, 4096)
    const float* W  = (const float*)d_in[1];   // (4096, 4096)
    const float* b  = (const float*)d_in[2];   // (4096,)
    const float* lA = (const float*)d_in[3];   // (16, 4096)
    const float* lB = (const float*)d_in[4];   // (4096, 16)
    float* out = (float*)d_out;                // (8192, 4096) fp32

    // workspace layout: Aw (8192 x 4160 bf16), Bw (4096 x 4160 bf16) ~102.3 MB
    bf16_t* Aw = (bf16_t*)d_ws;
    bf16_t* Bw = Aw + (size_t)N_ROWS * KP;

    prep_fused<<<PREPA_BLOCKS + OUT_F / 4, 256, 0, stream>>>(x, W, b, lA, lB, Aw, Bw);
    gemm_bt<<<(N_ROWS / BM) * (OUT_F / BN), 512, 0, stream>>>(Aw, Bw, out);
}

// Round 2
// 538.929 us; speedup vs baseline: 1.0491x; 1.0491x over previous
//
#include <hip/hip_runtime.h>
#include <hip/hip_bf16.h>
#include <stdint.h>

// Problem constants
#define N_ROWS 8192
#define IN_F   4096
#define OUT_F  4096
#define R_LORA 16
#define KP     4160   // padded K: 4096 data + col 4096 = bias-1.0 trick + zeros to /64

typedef __bf16 bf16_t;
typedef __attribute__((ext_vector_type(8))) __bf16 bf16x8;
typedef __attribute__((ext_vector_type(4))) __bf16 bf16x4;
typedef __attribute__((ext_vector_type(4))) float  f32x4;
typedef __attribute__((ext_vector_type(16))) float f32x16;

// ---------------------------------------------------------------------------
// async global->LDS, 16B per lane. LDS dest must be wave_base + lane*16.
// Per-lane SOURCE address is free-form (gather) — only the dest is constrained.
__device__ __forceinline__ void load16_lds(const bf16_t* g, bf16_t* l) {
    auto gp = (const __attribute__((address_space(1))) void*)g;
    auto lp = (__attribute__((address_space(3))) void*)(uint32_t)(uintptr_t)l;
    __builtin_amdgcn_global_load_lds(gp, lp, 16, 0, 0);
}

// ---------------------------------------------------------------------------
// Fused prep: blocks [0,2048) build Aw (4 rows each); blocks [2048,3072)
// build Bw (4 o-rows each). Unchanged this round (next optimization target).
#define PREPA_BLOCKS 2048

__global__ __launch_bounds__(256) void prep_fused(const float* __restrict__ x,
                                                  const float* __restrict__ W,
                                                  const float* __restrict__ bias,
                                                  const float* __restrict__ lA,
                                                  const float* __restrict__ lB,
                                                  bf16_t* __restrict__ Aw,
                                                  bf16_t* __restrict__ Bw) {
    int b = blockIdx.x;
    int t = threadIdx.x;
    if (b < PREPA_BLOCKS) {
        int row0 = b * 4;
        for (int rr = 0; rr < 4; ++rr) {
            int row = row0 + rr;
            const float4* xr = (const float4*)(x + (size_t)row * IN_F);
            bf16_t* ar = Aw + (size_t)row * KP;
            for (int s = t; s < 512; s += 256) {
                float4 f0 = xr[2 * s];
                float4 f1 = xr[2 * s + 1];
                bf16x8 v;
                v[0] = (bf16_t)f0.x; v[1] = (bf16_t)f0.y;
                v[2] = (bf16_t)f0.z; v[3] = (bf16_t)f0.w;
                v[4] = (bf16_t)f1.x; v[5] = (bf16_t)f1.y;
                v[6] = (bf16_t)f1.z; v[7] = (bf16_t)f1.w;
                *(bf16x8*)(ar + s * 8) = v;
            }
            if (t < 64) ar[IN_F + t] = (t == 0) ? (bf16_t)1.0f : (bf16_t)0.0f;
        }
    } else {
        int o0 = (b - PREPA_BLOCKS) * 4;
        float bl[4][R_LORA];
        for (int oo = 0; oo < 4; ++oo)
            for (int r = 0; r < R_LORA; ++r)
                bl[oo][r] = 2.0f * lB[(o0 + oo) * R_LORA + r];

        for (int j = 0; j < IN_F / (256 * 4); ++j) {   // 4 iterations
            int i4 = (j * 256 + t) * 4;
            f32x4 acc[4];
            for (int oo = 0; oo < 4; ++oo) {
                float4 w = *(const float4*)(W + (size_t)(o0 + oo) * IN_F + i4);
                acc[oo] = (f32x4){w.x, w.y, w.z, w.w};
            }
            for (int r = 0; r < R_LORA; ++r) {
                float4 a = *(const float4*)(lA + (size_t)r * IN_F + i4);
                for (int oo = 0; oo < 4; ++oo) {
                    acc[oo][0] += bl[oo][r] * a.x;
                    acc[oo][1] += bl[oo][r] * a.y;
                    acc[oo][2] += bl[oo][r] * a.z;
                    acc[oo][3] += bl[oo][r] * a.w;
                }
            }
            for (int oo = 0; oo < 4; ++oo) {
                bf16x4 v;
                v[0] = (bf16_t)acc[oo][0]; v[1] = (bf16_t)acc[oo][1];
                v[2] = (bf16_t)acc[oo][2]; v[3] = (bf16_t)acc[oo][3];
                *(bf16x4*)(Bw + (size_t)(o0 + oo) * KP + i4) = v;
            }
        }
        {   // pad columns: 4 rows x 64 cols = 256 slots, one per thread
            int oo = t >> 6;
            int c  = IN_F + (t & 63);
            float v = (c == IN_F) ? bias[o0 + oo] : 0.0f;
            Bw[(size_t)(o0 + oo) * KP + c] = (bf16_t)v;
        }
    }
}

// ---------------------------------------------------------------------------
// NT bf16 GEMM: C[8192x4096] = Aw[8192xKP] * Bw[4096xKP]^T  (fp32 out)
//
// 256x256 tile, BK=64, 512 thr = 8 waves in a 2x4 grid; per-wave output
// 128x64 = 4x2 fragments of 32x32 (acc = 128 f32). Each wave reads each of
// its A/B fragments exactly ONCE per K-tile: 16 A + 8 B = 24 ds_read_b128
// per wave per tile (R1's quadrant phasing read 48 -> LDS-read-bound at
// 39% MfmaUtil; this halves LDS traffic to balance with MFMA).
//
// Schedule per K-tile (2 barriers, 1 counted vmcnt, NO per-phase lockstep):
//   s_barrier                      // all reads of buf nb (tile kt-1) done
//   issue 8 global_load_lds (tile kt+1 -> buf nb)
//   s_waitcnt vmcnt(8)             // MY tile-kt loads landed (kt+1 flying)
//   s_barrier                      // => ALL waves' tile-kt loads landed
//   24 ds_read + 32 MFMA, compiler-scheduled, waves drift freely
// vmcnt never drains to 0 in the main loop; the wait targets loads issued a
// full tile (~4000 cyc) earlier, so it is non-blocking in steady state.
// The wait-THEN-barrier order is what makes other waves' DMA visible
// (per-wave vmcnt cannot observe another wave's loads).
//
// LDS XOR swizzle (verified R0/R1): LDS 16B-slot (r,p) holds global chunk
// (r, p ^ (r&7)); fragment reads use pos = (chunk ^ (lane&7))*8.
#define BM 256
#define BN 256
#define BK 64
#define NT (KP / BK)    // 65

__global__ __launch_bounds__(512, 2) void gemm_bt(const bf16_t* __restrict__ A,
                                                  const bf16_t* __restrict__ B,
                                                  float* __restrict__ C) {
    __shared__ __align__(16) bf16_t lds[2][2][BM * BK];   // 128 KiB

    int bid = blockIdx.x;
    // XCD-aware bijective swizzle (512 blocks % 8 == 0): each XCD owns a
    // 2-column stripe (2 B-panels = 4.3 MB ~ L2) across all row tiles.
    int swz = (bid & 7) * 64 + (bid >> 3);
    int bm  = swz & 31;              // 8192/256 = 32 row tiles
    int bn  = swz >> 5;              // 4096/256 = 16 col tiles
    int rowBase = bm * BM;
    int colBase = bn * BN;

    const int t    = threadIdx.x;
    const int lane = t & 63;
    const int wave = t >> 6;
    const int l31  = lane & 31;
    const int lhi  = lane >> 5;
    const int l7   = lane & 7;
    const int wr   = wave >> 2;      // 0..1: rows [wr*128, wr*128+128)
    const int wc   = wave & 3;       // 0..3: cols [wc*64,  wc*64+64)

    // per-fragment LDS element offsets (before the per-ks pos term)
    int rowOffA[4], colOffB[2];
#pragma unroll
    for (int rf = 0; rf < 4; ++rf) rowOffA[rf] = (wr * 128 + rf * 32 + l31) * BK;
#pragma unroll
    for (int cf = 0; cf < 2; ++cf) colOffB[cf] = (wc * 64 + cf * 32 + l31) * BK;

    // staging: chunk c = s*512 + t in [0,2048): r = c>>3 (256 rows), p = c&7.
    // LDS dest is linear (required by global_load_lds); swizzle is in SOURCE.
    uint32_t srcA[4], srcB[4];
#pragma unroll
    for (int s = 0; s < 4; ++s) {
        int c = s * 512 + t;
        int r = c >> 3, p = c & 7;
        uint32_t off = (uint32_t)(r * KP + ((p ^ (r & 7)) << 3));
        srcA[s] = (uint32_t)(rowBase * KP) + off;
        srcB[s] = (uint32_t)(colBase * KP) + off;
    }

    auto stage = [&](int bsel, int k0) {   // 8 gload_lds per thread
#pragma unroll
        for (int s = 0; s < 4; ++s)
            load16_lds(A + srcA[s] + k0, &lds[bsel][0][(s * 512 + t) * 8]);
#pragma unroll
        for (int s = 0; s < 4; ++s)
            load16_lds(B + srcB[s] + k0, &lds[bsel][1][(s * 512 + t) * 8]);
    };

    f32x16 acc[4][2];
#pragma unroll
    for (int rf = 0; rf < 4; ++rf)
#pragma unroll
        for (int cf = 0; cf < 2; ++cf)
#pragma unroll
            for (int r = 0; r < 16; ++r) acc[rf][cf][r] = 0.f;

#define COMPUTE(bsel)                                                          \
    do {                                                                       \
        const bf16_t* Ab = &lds[bsel][0][0];                                   \
        const bf16_t* Bb = &lds[bsel][1][0];                                   \
        _Pragma("unroll")                                                      \
        for (int ks = 0; ks < 4; ++ks) {                                       \
            int pos = ((((ks << 1) | lhi)) ^ l7) << 3;                         \
            bf16x8 af[4], bf[2];                                               \
            _Pragma("unroll")                                                  \
            for (int rf = 0; rf < 4; ++rf)                                     \
                af[rf] = *(const bf16x8*)&Ab[rowOffA[rf] + pos];               \
            _Pragma("unroll")                                                  \
            for (int cf = 0; cf < 2; ++cf)                                     \
                bf[cf] = *(const bf16x8*)&Bb[colOffB[cf] + pos];               \
            __builtin_amdgcn_s_setprio(1);                                     \
            _Pragma("unroll")                                                  \
            for (int rf = 0; rf < 4; ++rf)                                     \
                _Pragma("unroll")                                              \
                for (int cf = 0; cf < 2; ++cf)                                 \
                    acc[rf][cf] = __builtin_amdgcn_mfma_f32_32x32x16_bf16(     \
                        af[rf], bf[cf], acc[rf][cf], 0, 0, 0);                 \
            __builtin_amdgcn_s_setprio(0);                                     \
        }                                                                      \
    } while (0)

    // prologue: tile 0 -> buf 0
    stage(0, 0);

    for (int kt = 0; kt < NT - 1; ++kt) {
        const int cur = kt & 1;
        const int nb  = cur ^ 1;
        __builtin_amdgcn_s_barrier();                  // reads of buf nb done
        stage(nb, (kt + 1) * BK);                      // tile kt+1 -> buf nb
        asm volatile("s_waitcnt vmcnt(8)" ::: "memory");   // tile kt landed
        __builtin_amdgcn_s_barrier();                  // ...for ALL waves
        COMPUTE(cur);
    }
    {   // tail: kt = NT-1 (= 64, buf 0); nothing left to issue
        __builtin_amdgcn_s_barrier();
        asm volatile("s_waitcnt vmcnt(0)" ::: "memory");
        __builtin_amdgcn_s_barrier();
        COMPUTE(0);
    }
#undef COMPUTE

    // epilogue: C/D layout col=l&31, row=(reg&3)+8*(reg>>2)+4*(l>>5)
#pragma unroll
    for (int rf = 0; rf < 4; ++rf) {
        int rB = rowBase + wr * 128 + rf * 32 + 4 * lhi;
#pragma unroll
        for (int cf = 0; cf < 2; ++cf) {
            int col = colBase + wc * 64 + cf * 32 + l31;
#pragma unroll
            for (int reg = 0; reg < 16; ++reg) {
                int row = rB + (reg & 3) + 8 * (reg >> 2);
                C[(size_t)row * OUT_F + col] = acc[rf][cf][reg];
            }
        }
    }
}

// ---------------------------------------------------------------------------
extern "C" void kernel_launch(void* const* d_in, const int* in_sizes, int n_in,
                              void* d_out, int out_size, void* d_ws, size_t ws_size,
                              hipStream_t stream) {
    const float* x  = (const float*)d_in[0];   // (8192, 4096)
    const float* W  = (const float*)d_in[1];   // (4096, 4096)
    const float* b  = (const float*)d_in[2];   // (4096,)
    const float* lA = (const float*)d_in[3];   // (16, 4096)
    const float* lB = (const float*)d_in[4];   // (4096, 16)
    float* out = (float*)d_out;                // (8192, 4096) fp32

    // workspace layout: Aw (8192 x 4160 bf16), Bw (4096 x 4160 bf16) ~102.3 MB
    bf16_t* Aw = (bf16_t*)d_ws;
    bf16_t* Bw = Aw + (size_t)N_ROWS * KP;

    prep_fused<<<PREPA_BLOCKS + OUT_F / 4, 256, 0, stream>>>(x, W, b, lA, lB, Aw, Bw);
    gemm_bt<<<(N_ROWS / BM) * (OUT_F / BN), 512, 0, stream>>>(Aw, Bw, out);
}